// Round 2
// baseline (2547.406 us; speedup 1.0000x reference)
//
#include <hip/hip_runtime.h>
#include <stdint.h>

// EdgeConv fused: out[i] = max over edges (j->i) of MLP3(concat[x_i, x_j-x_i])
// Layer-1 split: e@W1 = x_i@(W1a-W1b) + x_j@W1b  (W1a=W1[0:128], W1b=W1[128:256])
// Per-node precompute a=x@(W1a-W1b)+b1, c=x@W1b (bf16). Per-edge: h1=relu(a[dst]+c[src]),
// two bf16-MFMA GEMMs (transposed chain, h2 in-place over h1), register atomic-max scatter.
// Round 2: 32 edges/block, 16.6KB LDS, launch_bounds(256,6) -> ~24 waves/CU (was 8).

#define N_NODES 50000
#define N_EDGES 800000

typedef __attribute__((ext_vector_type(4))) float f32x4;
typedef __attribute__((ext_vector_type(8))) short s16x8;
typedef __attribute__((ext_vector_type(4))) unsigned int u32x4;
typedef __attribute__((ext_vector_type(2))) unsigned int u32x2;

__device__ __forceinline__ float bf2f(unsigned int b){ return __builtin_bit_cast(float, b << 16); }
__device__ __forceinline__ unsigned int f2bf(float f){          // RNE f32->bf16, low 16 bits
  unsigned int u = __builtin_bit_cast(unsigned int, f);
  return (u + 0x7FFFu + ((u >> 16) & 1u)) >> 16;
}
__device__ __forceinline__ unsigned int pk2(float lo, float hi){ return f2bf(lo) | (f2bf(hi) << 16); }
// monotone float->uint map: f1<f2 <=> map(f1)<map(f2); any real value maps > 0
__device__ __forceinline__ unsigned int fmap(float f){
  unsigned int u = __builtin_bit_cast(unsigned int, f);
  return (u & 0x80000000u) ? ~u : (u | 0x80000000u);
}

// ---- detect edge_index element width: int64 (odd u32 slots all zero) vs int32 ----
extern "C" __global__ void k_detect(const unsigned int* __restrict__ e, int* __restrict__ flag){
  unsigned int v = e[2 * threadIdx.x + 1];
  unsigned long long b = __ballot(v != 0u);
  if (threadIdx.x == 0) *flag = (b == 0ull) ? 1 : 0;   // 1 => int64
}

// ---- pre-swizzle W2^T / W3^T into MFMA A-frag order, bf16 ----
// A-frag (16x16x32): lane l holds A[m=16*mfG+(l&15)][k=32*ks+8*(l>>4)+j], j=0..7
extern "C" __global__ void k_wswz(const float* __restrict__ W2, const float* __restrict__ W3,
                                  unsigned short* __restrict__ w2s, unsigned short* __restrict__ w3s){
  int t = blockIdx.x * 256 + threadIdx.x;              // 0..16383
  const float* W = (t & 8192) ? W3 : W2;
  unsigned short* o = (t & 8192) ? w3s : w2s;
  int r = t & 8191;
  int lane = r & 63, blk = r >> 6;
  int mfG = blk >> 3, ks = blk & 7;
  int m  = mfG * 16 + (lane & 15);
  int k0 = ks * 32 + (lane >> 4) * 8;
  u32x4 ov;
  #pragma unroll
  for (int j = 0; j < 4; j++){
    unsigned int lo = f2bf(W[(size_t)(k0 + 2*j    ) * 256 + m]);   // A[m][k] = W[k][m]
    unsigned int hi = f2bf(W[(size_t)(k0 + 2*j + 1) * 256 + m]);
    ov[j] = lo | (hi << 16);
  }
  *(u32x4*)(o + (size_t)r * 8) = ov;
}

// ---- per-node precompute: a = x@(W1a-W1b)+b1, c = x@W1b  (fp32 math, bf16 out) ----
// x reads are wave-uniform -> scalar loads; W1 reads coalesced across threads. No LDS.
extern "C" __global__ void __launch_bounds__(512) k_ac(
    const float* __restrict__ x, const float* __restrict__ W1, const float* __restrict__ b1,
    unsigned short* __restrict__ a, unsigned short* __restrict__ cc){
  const int t = threadIdx.x;
  const int n0 = blockIdx.x * 16;                      // 3125 blocks exactly
  const int col = t & 255, half = t >> 8;              // half 0 -> a, 1 -> c (wave-uniform)
  float acc[16];
  #pragma unroll
  for (int r = 0; r < 16; r++) acc[r] = 0.f;
  const float* wb = W1 + 128 * 256 + col;              // W1b column
  const float* xb = x + (size_t)n0 * 128;
  #pragma unroll 4
  for (int k = 0; k < 128; k++){
    float wv = wb[(size_t)k * 256];
    if (half == 0) wv = W1[(size_t)k * 256 + col] - wv;
    #pragma unroll
    for (int r = 0; r < 16; r++) acc[r] += xb[r * 128 + k] * wv;   // xb[..]: uniform -> s_load
  }
  float bias = (half == 0) ? b1[col] : 0.f;
  unsigned short* o = (half == 0) ? a : cc;
  #pragma unroll
  for (int r = 0; r < 16; r++)
    o[(size_t)(n0 + r) * 256 + col] = (unsigned short)f2bf(acc[r] + bias);
}

// ---- fused edge MLP: 32 edges/block, 4 waves; transposed MFMA chain ----
// LDS: one 16KB buffer [32 rows][512B], XOR-swizzled byte ^= (row&7)<<4.
// h1 lives there for G1; after a barrier h2 (bias2+relu, bf16) overwrites it for G2.
// h3 never touches LDS: bias3 + atomic-max scatter straight from D-fragments.
extern "C" __global__ void __launch_bounds__(256, 6) k_edge(
    const unsigned short* __restrict__ a, const unsigned short* __restrict__ c,
    const s16x8* __restrict__ w2f, const s16x8* __restrict__ w3f,
    const float* __restrict__ b2, const float* __restrict__ b3,
    const void* __restrict__ eidx, const int* __restrict__ flag,
    unsigned int* __restrict__ outu){
  __shared__ unsigned char sm[16384];
  __shared__ int dstI[32];
  __shared__ int srcI[32];
  const int tid = threadIdx.x;
  const int lane = tid & 63;
  const int w = tid >> 6;
  const int e0 = blockIdx.x * 32;

  if (tid < 32){
    int s, d;
    if (*flag){
      const long long* p = (const long long*)eidx;
      s = (int)p[e0 + tid]; d = (int)p[N_EDGES + e0 + tid];
    } else {
      const int* p = (const int*)eidx;
      s = p[e0 + tid]; d = p[N_EDGES + e0 + tid];
    }
    srcI[tid] = s; dstI[tid] = d;
  }
  __syncthreads();

  { // gather: h1 = relu(a[dst] + c[src]) -> sm bf16 swizzled. 8 threads/edge, 64B each.
    const int e = tid >> 3, q = tid & 7;
    const unsigned short* pa = a + (size_t)dstI[e] * 256 + q * 32;
    const unsigned short* pc = c + (size_t)srcI[e] * 256 + q * 32;
    unsigned char* rowp = sm + e * 512;
    const int sw = (e & 7) << 4;
    #pragma unroll
    for (int j = 0; j < 4; j++){
      u32x4 ua = *(const u32x4*)(pa + j * 8);
      u32x4 uc = *(const u32x4*)(pc + j * 8);
      u32x4 ov;
      #pragma unroll
      for (int t2 = 0; t2 < 4; t2++){
        float lo = bf2f(ua[t2] & 0xFFFFu) + bf2f(uc[t2] & 0xFFFFu);
        float hi = bf2f(ua[t2] >> 16)     + bf2f(uc[t2] >> 16);
        ov[t2] = pk2(fmaxf(lo, 0.f), fmaxf(hi, 0.f));
      }
      *(u32x4*)(rowp + ((q * 64 + j * 16) ^ sw)) = ov;
    }
  }
  __syncthreads();

  const int lm = lane & 15, g = lane >> 4;
  f32x4 acc[4][2];
  #pragma unroll
  for (int mf = 0; mf < 4; mf++)
    #pragma unroll
    for (int nf = 0; nf < 2; nf++) acc[mf][nf] = (f32x4){0.f, 0.f, 0.f, 0.f};

  // G1: h2^T = W2^T @ h1^T   (A from pre-swizzled global/L2, B from LDS)
  #pragma unroll
  for (int ks = 0; ks < 8; ks++){
    s16x8 af[4], bf[2];
    #pragma unroll
    for (int mf = 0; mf < 4; mf++) af[mf] = w2f[((w * 4 + mf) * 8 + ks) * 64 + lane];
    #pragma unroll
    for (int nf = 0; nf < 2; nf++){
      int row = nf * 16 + lm;
      bf[nf] = *(const s16x8*)(sm + row * 512 + ((ks * 64 + g * 16) ^ ((row & 7) << 4)));
    }
    #pragma unroll
    for (int mf = 0; mf < 4; mf++)
      #pragma unroll
      for (int nf = 0; nf < 2; nf++)
        acc[mf][nf] = __builtin_amdgcn_mfma_f32_16x16x32_bf16(af[mf], bf[nf], acc[mf][nf], 0, 0, 0);
  }
  __syncthreads();   // all waves done READING h1 before h2 overwrites it

  { // bias2 + relu -> h2 bf16 swizzled, in place (each wave owns channel slice w*64..)
    #pragma unroll
    for (int mf = 0; mf < 4; mf++){
      const int m0 = w * 64 + mf * 16 + g * 4;
      const f32x4 bb = *(const f32x4*)(b2 + m0);
      #pragma unroll
      for (int nf = 0; nf < 2; nf++){
        int row = nf * 16 + lm;
        float v0 = fmaxf(acc[mf][nf][0] + bb[0], 0.f);
        float v1 = fmaxf(acc[mf][nf][1] + bb[1], 0.f);
        float v2 = fmaxf(acc[mf][nf][2] + bb[2], 0.f);
        float v3 = fmaxf(acc[mf][nf][3] + bb[3], 0.f);
        u32x2 pv = { pk2(v0, v1), pk2(v2, v3) };
        *(u32x2*)(sm + row * 512 + ((m0 * 2) ^ ((row & 7) << 4))) = pv;
      }
    }
  }
  __syncthreads();

  // G2: h3^T = W3^T @ h2^T
  f32x4 acc2[4][2];
  #pragma unroll
  for (int mf = 0; mf < 4; mf++)
    #pragma unroll
    for (int nf = 0; nf < 2; nf++) acc2[mf][nf] = (f32x4){0.f, 0.f, 0.f, 0.f};
  #pragma unroll
  for (int ks = 0; ks < 8; ks++){
    s16x8 af[4], bf[2];
    #pragma unroll
    for (int mf = 0; mf < 4; mf++) af[mf] = w3f[((w * 4 + mf) * 8 + ks) * 64 + lane];
    #pragma unroll
    for (int nf = 0; nf < 2; nf++){
      int row = nf * 16 + lm;
      bf[nf] = *(const s16x8*)(sm + row * 512 + ((ks * 64 + g * 16) ^ ((row & 7) << 4)));
    }
    #pragma unroll
    for (int mf = 0; mf < 4; mf++)
      #pragma unroll
      for (int nf = 0; nf < 2; nf++)
        acc2[mf][nf] = __builtin_amdgcn_mfma_f32_16x16x32_bf16(af[mf], bf[nf], acc2[mf][nf], 0, 0, 0);
  }

  // bias3 + atomic-max scatter straight from registers.
  // D-frag: lane holds channels m0..m0+3 (consecutive) for edge row nf*16+lm.
  #pragma unroll
  for (int mf = 0; mf < 4; mf++){
    const int m0 = w * 64 + mf * 16 + g * 4;
    const f32x4 bb = *(const f32x4*)(b3 + m0);
    #pragma unroll
    for (int nf = 0; nf < 2; nf++){
      const int row = nf * 16 + lm;
      unsigned int* p = outu + (size_t)dstI[row] * 256 + m0;
      #pragma unroll
      for (int j = 0; j < 4; j++){
        unsigned int mu = fmap(acc2[mf][nf][j] + bb[j]);
        if (mu > p[j]) atomicMax(p + j, mu);   // read-test safe: cell only grows
      }
    }
  }
}

// ---- unmap uint->float; untouched (0) cells = empty segments -> 0.0 ----
extern "C" __global__ void k_fix(unsigned int* __restrict__ o){
  size_t i = (size_t)blockIdx.x * 256 + threadIdx.x;
  unsigned int u = o[i];
  o[i] = (u == 0u) ? 0u : ((u & 0x80000000u) ? (u ^ 0x80000000u) : ~u);
}

extern "C" void kernel_launch(void* const* d_in, const int* in_sizes, int n_in,
                              void* d_out, int out_size, void* d_ws, size_t ws_size,
                              hipStream_t stream){
  const float* x  = (const float*)d_in[0];
  const void*  ei = d_in[1];
  const float* W1 = (const float*)d_in[2];
  const float* b1 = (const float*)d_in[3];
  const float* W2 = (const float*)d_in[4];
  const float* b2 = (const float*)d_in[5];
  const float* W3 = (const float*)d_in[6];
  const float* b3 = (const float*)d_in[7];

  const size_t A_BYTES = (size_t)N_NODES * 256 * 2;   // 25.6 MB each for a, c
  const size_t W_BYTES = 256 * 256 * 2;               // 128 KB each swizzled weight
  char* ws = (char*)d_ws;
  unsigned short* a   = (unsigned short*)(ws);
  unsigned short* cc  = (unsigned short*)(ws + A_BYTES);
  unsigned short* w2s = (unsigned short*)(ws + 2 * A_BYTES);
  unsigned short* w3s = (unsigned short*)(ws + 2 * A_BYTES + W_BYTES);
  int* flag           = (int*)(ws + 2 * A_BYTES + 2 * W_BYTES);
  if (ws_size < 2 * A_BYTES + 2 * W_BYTES + 16) return;   // insufficient scratch

  k_detect<<<1, 64, 0, stream>>>((const unsigned int*)ei, flag);
  k_wswz<<<64, 256, 0, stream>>>(W2, W3, w2s, w3s);
  k_ac<<<N_NODES / 16, 512, 0, stream>>>(x, W1, b1, a, cc);
  hipMemsetAsync(d_out, 0, (size_t)out_size * 4, stream);
  k_edge<<<N_EDGES / 32, 256, 0, stream>>>(a, cc, (const s16x8*)w2s, (const s16x8*)w3s,
                                           b2, b3, ei, flag, (unsigned int*)d_out);
  k_fix<<<(out_size + 255) / 256, 256, 0, stream>>>((unsigned int*)d_out);
}

// Round 3
// 766.050 us; speedup vs baseline: 3.3254x; 3.3254x over previous
//
#include <hip/hip_runtime.h>
#include <stdint.h>

// EdgeConv fused: out[i] = max over edges (j->i) of MLP3(concat[x_i, x_j-x_i])
// Layer-1 split: e@W1 = x_i@(W1a-W1b) + x_j@W1b. Per-node a=x@(W1a-W1b)+b1, c=x@W1b (bf16).
// Round 3: counting-sort edges by dst -> a-gather becomes cache-hot, per-dst-group
// running-max in registers -> ~5 coalesced atomic bursts per block instead of 64.
// k_edge: 64 edges/block, 33KB LDS (h1 -> h2 in-place -> h3 staged in two 32-row halves).

#define N_NODES 50000
#define N_EDGES 800000

typedef __attribute__((ext_vector_type(4))) float f32x4;
typedef __attribute__((ext_vector_type(8))) short s16x8;
typedef __attribute__((ext_vector_type(4))) unsigned int u32x4;
typedef __attribute__((ext_vector_type(2))) unsigned int u32x2;

__device__ __forceinline__ float bf2f(unsigned int b){ return __builtin_bit_cast(float, b << 16); }
__device__ __forceinline__ unsigned int f2bf(float f){          // RNE f32->bf16, low 16 bits
  unsigned int u = __builtin_bit_cast(unsigned int, f);
  return (u + 0x7FFFu + ((u >> 16) & 1u)) >> 16;
}
__device__ __forceinline__ unsigned int pk2(float lo, float hi){ return f2bf(lo) | (f2bf(hi) << 16); }
// monotone float->uint map: f1<f2 <=> map(f1)<map(f2); any finite value maps to nonzero
__device__ __forceinline__ unsigned int fmap(float f){
  unsigned int u = __builtin_bit_cast(unsigned int, f);
  return (u & 0x80000000u) ? ~u : (u | 0x80000000u);
}

// ---- detect edge_index element width: int64 (odd u32 slots all zero) vs int32 ----
extern "C" __global__ void k_detect(const unsigned int* __restrict__ e, int* __restrict__ flag){
  unsigned int v = e[2 * threadIdx.x + 1];
  unsigned long long b = __ballot(v != 0u);
  if (threadIdx.x == 0) *flag = (b == 0ull) ? 1 : 0;   // 1 => int64
}

// ---- counting sort by dst: histogram ----
extern "C" __global__ void k_hist(const void* __restrict__ eidx, const int* __restrict__ flag,
                                  unsigned int* __restrict__ cnt){
  int i = blockIdx.x * 256 + threadIdx.x;
  int d = (*flag) ? (int)((const long long*)eidx)[N_EDGES + i]
                  : ((const int*)eidx)[N_EDGES + i];
  atomicAdd(&cnt[d], 1u);
}

// ---- single-block exclusive scan over 50000 counters ----
extern "C" __global__ void __launch_bounds__(1024) k_scan(const unsigned int* __restrict__ cnt,
                                                          unsigned int* __restrict__ off){
  __shared__ unsigned int ps[1024];
  const int t = threadIdx.x;
  const int lo = t * 49;
  const int hi = (lo + 49 < N_NODES) ? lo + 49 : N_NODES;   // 49*1024 = 50176 >= 50000
  unsigned int s = 0;
  for (int i = lo; i < hi; i++) s += cnt[i];
  ps[t] = s; __syncthreads();
  for (int d = 1; d < 1024; d <<= 1){
    unsigned int v = (t >= d) ? ps[t - d] : 0u;
    __syncthreads();
    ps[t] += v;
    __syncthreads();
  }
  unsigned int run = (t > 0) ? ps[t - 1] : 0u;
  for (int i = lo; i < hi; i++){ off[i] = run; run += cnt[i]; }
}

// ---- scatter edges into dst-sorted order, packed (src | dst<<16), consuming off as cursor ----
extern "C" __global__ void k_bucket(const void* __restrict__ eidx, const int* __restrict__ flag,
                                    unsigned int* __restrict__ cur, unsigned int* __restrict__ sPair){
  int i = blockIdx.x * 256 + threadIdx.x;
  int s, d;
  if (*flag){
    const long long* p = (const long long*)eidx;
    s = (int)p[i]; d = (int)p[N_EDGES + i];
  } else {
    const int* p = (const int*)eidx;
    s = p[i]; d = p[N_EDGES + i];
  }
  unsigned int pos = atomicAdd(&cur[d], 1u);
  sPair[pos] = (unsigned int)s | ((unsigned int)d << 16);    // both < 50000 < 2^16
}

// ---- pre-swizzle W2^T / W3^T into MFMA A-frag order, bf16 ----
extern "C" __global__ void k_wswz(const float* __restrict__ W2, const float* __restrict__ W3,
                                  unsigned short* __restrict__ w2s, unsigned short* __restrict__ w3s){
  int t = blockIdx.x * 256 + threadIdx.x;              // 0..16383
  const float* W = (t & 8192) ? W3 : W2;
  unsigned short* o = (t & 8192) ? w3s : w2s;
  int r = t & 8191;
  int lane = r & 63, blk = r >> 6;
  int mfG = blk >> 3, ks = blk & 7;
  int m  = mfG * 16 + (lane & 15);
  int k0 = ks * 32 + (lane >> 4) * 8;
  u32x4 ov;
  #pragma unroll
  for (int j = 0; j < 4; j++){
    unsigned int lo = f2bf(W[(size_t)(k0 + 2*j    ) * 256 + m]);   // A[m][k] = W[k][m]
    unsigned int hi = f2bf(W[(size_t)(k0 + 2*j + 1) * 256 + m]);
    ov[j] = lo | (hi << 16);
  }
  *(u32x4*)(o + (size_t)r * 8) = ov;
}

// ---- per-node precompute: a = x@(W1a-W1b)+b1, c = x@W1b  (fp32 math, bf16 out) ----
extern "C" __global__ void __launch_bounds__(512) k_ac(
    const float* __restrict__ x, const float* __restrict__ W1, const float* __restrict__ b1,
    unsigned short* __restrict__ a, unsigned short* __restrict__ cc){
  const int t = threadIdx.x;
  const int n0 = blockIdx.x * 16;                      // 3125 blocks exactly
  const int col = t & 255, half = t >> 8;              // half 0 -> a, 1 -> c (wave-uniform)
  float acc[16];
  #pragma unroll
  for (int r = 0; r < 16; r++) acc[r] = 0.f;
  const float* wb = W1 + 128 * 256 + col;              // W1b column
  const float* xb = x + (size_t)n0 * 128;
  #pragma unroll 4
  for (int k = 0; k < 128; k++){
    float wv = wb[(size_t)k * 256];
    if (half == 0) wv = W1[(size_t)k * 256 + col] - wv;
    #pragma unroll
    for (int r = 0; r < 16; r++) acc[r] += xb[r * 128 + k] * wv;   // uniform -> s_load
  }
  float bias = (half == 0) ? b1[col] : 0.f;
  unsigned short* o = (half == 0) ? a : cc;
  #pragma unroll
  for (int r = 0; r < 16; r++)
    o[(size_t)(n0 + r) * 256 + col] = (unsigned short)f2bf(acc[r] + bias);
}

// ---- fused edge MLP on dst-sorted edges: 64 edges/block, 4 waves ----
// LDS: one 32KB buffer, XOR-swizzled. h1 (bf16) -> G1 -> h2 in-place (bf16) -> G2 ->
// h3 staged f32 in two 32-row halves -> per-dst-group running-max scatter.
extern "C" __global__ void __launch_bounds__(256, 4) k_edge(
    const unsigned short* __restrict__ a, const unsigned short* __restrict__ c,
    const s16x8* __restrict__ w2f, const s16x8* __restrict__ w3f,
    const float* __restrict__ b2, const float* __restrict__ b3,
    const unsigned int* __restrict__ sPair,
    unsigned int* __restrict__ outu){
  __shared__ unsigned char sm[32768];
  __shared__ int dstI[64];
  __shared__ int srcI[64];
  const int tid = threadIdx.x;
  const int lane = tid & 63;
  const int w = tid >> 6;
  const int e0 = blockIdx.x * 64;

  if (tid < 64){
    unsigned int pr = sPair[e0 + tid];
    srcI[tid] = (int)(pr & 0xFFFFu);
    dstI[tid] = (int)(pr >> 16);
  }
  __syncthreads();

  { // gather: h1 = relu(a[dst] + c[src]) -> sm bf16 swizzled. 4 threads/edge, 128B each.
    const int e = tid >> 2, q = tid & 3;
    const unsigned short* pa = a + (size_t)dstI[e] * 256 + q * 64;   // sorted: L1/L2-hot
    const unsigned short* pc = c + (size_t)srcI[e] * 256 + q * 64;
    unsigned char* rowp = sm + e * 512;
    const int sw = (e & 7) << 4;
    #pragma unroll
    for (int j = 0; j < 8; j++){
      u32x4 ua = *(const u32x4*)(pa + j * 8);
      u32x4 uc = *(const u32x4*)(pc + j * 8);
      u32x4 ov;
      #pragma unroll
      for (int t2 = 0; t2 < 4; t2++){
        float lo = bf2f(ua[t2] & 0xFFFFu) + bf2f(uc[t2] & 0xFFFFu);
        float hi = bf2f(ua[t2] >> 16)     + bf2f(uc[t2] >> 16);
        ov[t2] = pk2(fmaxf(lo, 0.f), fmaxf(hi, 0.f));
      }
      *(u32x4*)(rowp + ((q * 128 + j * 16) ^ sw)) = ov;
    }
  }
  __syncthreads();

  const int lm = lane & 15, g = lane >> 4;
  f32x4 acc[4][4];
  #pragma unroll
  for (int mf = 0; mf < 4; mf++)
    #pragma unroll
    for (int nf = 0; nf < 4; nf++) acc[mf][nf] = (f32x4){0.f, 0.f, 0.f, 0.f};

  // G1: h2^T = W2^T @ h1^T
  #pragma unroll
  for (int ks = 0; ks < 8; ks++){
    s16x8 af[4], bfr[4];
    #pragma unroll
    for (int mf = 0; mf < 4; mf++) af[mf] = w2f[((w * 4 + mf) * 8 + ks) * 64 + lane];
    #pragma unroll
    for (int nf = 0; nf < 4; nf++){
      int row = nf * 16 + lm;
      bfr[nf] = *(const s16x8*)(sm + row * 512 + ((ks * 64 + g * 16) ^ ((row & 7) << 4)));
    }
    #pragma unroll
    for (int mf = 0; mf < 4; mf++)
      #pragma unroll
      for (int nf = 0; nf < 4; nf++)
        acc[mf][nf] = __builtin_amdgcn_mfma_f32_16x16x32_bf16(af[mf], bfr[nf], acc[mf][nf], 0, 0, 0);
  }
  __syncthreads();   // all waves done reading h1

  { // bias2 + relu -> h2 bf16 swizzled, in place
    #pragma unroll
    for (int mf = 0; mf < 4; mf++){
      const int m0 = w * 64 + mf * 16 + g * 4;
      const f32x4 bb = *(const f32x4*)(b2 + m0);
      #pragma unroll
      for (int nf = 0; nf < 4; nf++){
        int row = nf * 16 + lm;
        float v0 = fmaxf(acc[mf][nf][0] + bb[0], 0.f);
        float v1 = fmaxf(acc[mf][nf][1] + bb[1], 0.f);
        float v2 = fmaxf(acc[mf][nf][2] + bb[2], 0.f);
        float v3 = fmaxf(acc[mf][nf][3] + bb[3], 0.f);
        u32x2 pv = { pk2(v0, v1), pk2(v2, v3) };
        *(u32x2*)(sm + row * 512 + ((m0 * 2) ^ ((row & 7) << 4))) = pv;
      }
    }
  }
  __syncthreads();

  // G2: h3^T = W3^T @ h2^T  (reuse acc)
  #pragma unroll
  for (int mf = 0; mf < 4; mf++)
    #pragma unroll
    for (int nf = 0; nf < 4; nf++) acc[mf][nf] = (f32x4){0.f, 0.f, 0.f, 0.f};
  #pragma unroll
  for (int ks = 0; ks < 8; ks++){
    s16x8 af[4], bfr[4];
    #pragma unroll
    for (int mf = 0; mf < 4; mf++) af[mf] = w3f[((w * 4 + mf) * 8 + ks) * 64 + lane];
    #pragma unroll
    for (int nf = 0; nf < 4; nf++){
      int row = nf * 16 + lm;
      bfr[nf] = *(const s16x8*)(sm + row * 512 + ((ks * 64 + g * 16) ^ ((row & 7) << 4)));
    }
    #pragma unroll
    for (int mf = 0; mf < 4; mf++)
      #pragma unroll
      for (int nf = 0; nf < 4; nf++)
        acc[mf][nf] = __builtin_amdgcn_mfma_f32_16x16x32_bf16(af[mf], bfr[nf], acc[mf][nf], 0, 0, 0);
  }
  __syncthreads();   // all h2 reads done before h3 staging overwrites the buffer

  // h3 staging + per-dst-group running-max scatter, two 32-row halves in 32KB.
  unsigned int vmax = 0;
  int curDst = dstI[0];
  #pragma unroll
  for (int half = 0; half < 2; half++){
    #pragma unroll
    for (int mf = 0; mf < 4; mf++){
      const int m0 = w * 64 + mf * 16 + g * 4;
      const f32x4 bb = *(const f32x4*)(b3 + m0);
      #pragma unroll
      for (int nfl = 0; nfl < 2; nfl++){
        const int r = nfl * 16 + lm;                    // row within half
        const int nf = half * 2 + nfl;
        f32x4 v = { acc[mf][nf][0] + bb[0], acc[mf][nf][1] + bb[1],
                    acc[mf][nf][2] + bb[2], acc[mf][nf][3] + bb[3] };
        *(f32x4*)(sm + r * 1024 + ((m0 * 4) ^ ((r & 7) << 4))) = v;
      }
    }
    __syncthreads();
    for (int it = 0; it < 32; it++){
      float v = *(const float*)(sm + it * 1024 + ((tid * 4) ^ ((it & 7) << 4)));
      const int d = dstI[half * 32 + it];               // uniform across block
      if (d != curDst){                                 // flush previous group (coalesced 1KB)
        unsigned int* p = outu + (size_t)curDst * 256 + tid;
        if (vmax > *p) atomicMax(p, vmax);
        curDst = d; vmax = 0;
      }
      unsigned int mu = fmap(v);
      vmax = (vmax > mu) ? vmax : mu;
    }
    __syncthreads();                                    // scatter reads done before next staging
  }
  { // final flush
    unsigned int* p = outu + (size_t)curDst * 256 + tid;
    if (vmax > *p) atomicMax(p, vmax);
  }
}

// ---- unmap uint->float; untouched (0) cells = empty segments -> 0.0 ----
extern "C" __global__ void k_fix(unsigned int* __restrict__ o){
  size_t i = (size_t)blockIdx.x * 256 + threadIdx.x;
  unsigned int u = o[i];
  o[i] = (u == 0u) ? 0u : ((u & 0x80000000u) ? (u ^ 0x80000000u) : ~u);
}

extern "C" void kernel_launch(void* const* d_in, const int* in_sizes, int n_in,
                              void* d_out, int out_size, void* d_ws, size_t ws_size,
                              hipStream_t stream){
  const float* x  = (const float*)d_in[0];
  const void*  ei = d_in[1];
  const float* W1 = (const float*)d_in[2];
  const float* b1 = (const float*)d_in[3];
  const float* W2 = (const float*)d_in[4];
  const float* b2 = (const float*)d_in[5];
  const float* W3 = (const float*)d_in[6];
  const float* b3 = (const float*)d_in[7];

  const size_t A_BYTES = (size_t)N_NODES * 256 * 2;   // 25.6 MB each for a, c
  const size_t W_BYTES = 256 * 256 * 2;               // 128 KB each swizzled weight
  const size_t P_BYTES = (size_t)N_EDGES * 4;         // 3.2 MB sorted pairs
  const size_t C_BYTES = 200704;                      // 50000 u32, padded to 256B multiple
  char* ws = (char*)d_ws;
  size_t o = 0;
  unsigned short* a    = (unsigned short*)(ws + o); o += A_BYTES;
  unsigned short* cc   = (unsigned short*)(ws + o); o += A_BYTES;
  unsigned short* w2s  = (unsigned short*)(ws + o); o += W_BYTES;
  unsigned short* w3s  = (unsigned short*)(ws + o); o += W_BYTES;
  unsigned int*  sPair = (unsigned int*)(ws + o);   o += P_BYTES;
  unsigned int*  cnt   = (unsigned int*)(ws + o);   o += C_BYTES;
  unsigned int*  offA  = (unsigned int*)(ws + o);   o += C_BYTES;
  int* flag            = (int*)(ws + o);            o += 256;
  if (ws_size < o) return;   // insufficient scratch

  k_detect<<<1, 64, 0, stream>>>((const unsigned int*)ei, flag);
  hipMemsetAsync(cnt, 0, C_BYTES, stream);
  k_hist<<<N_EDGES / 256, 256, 0, stream>>>(ei, flag, cnt);
  k_scan<<<1, 1024, 0, stream>>>(cnt, offA);
  k_bucket<<<N_EDGES / 256, 256, 0, stream>>>(ei, flag, offA, sPair);
  k_wswz<<<64, 256, 0, stream>>>(W2, W3, w2s, w3s);
  k_ac<<<N_NODES / 16, 512, 0, stream>>>(x, W1, b1, a, cc);
  hipMemsetAsync(d_out, 0, (size_t)out_size * 4, stream);
  k_edge<<<N_EDGES / 64, 256, 0, stream>>>(a, cc, (const s16x8*)w2s, (const s16x8*)w3s,
                                           b2, b3, sPair, (unsigned int*)d_out);
  k_fix<<<(out_size + 255) / 256, 256, 0, stream>>>((unsigned int*)d_out);
}

// Round 4
// 685.756 us; speedup vs baseline: 3.7147x; 1.1171x over previous
//
#include <hip/hip_runtime.h>
#include <stdint.h>

// EdgeConv fused: out[i] = max over edges (j->i) of MLP3(concat[x_i, x_j-x_i])
// Layer-1 split: e@W1 = x_i@(W1a-W1b) + x_j@W1b. Per-node a=x@(W1a-W1b)+b1, c=x@W1b (bf16).
// Counting-sort edges by dst; k_edge: 64 edges/block, fragment-linear LDS (conflict-free
// ds_read_b128), cvt_pk bf16 packing, float-domain running max, fire-and-forget atomics.

#define N_NODES 50000
#define N_EDGES 800000

typedef __attribute__((ext_vector_type(4))) float f32x4;
typedef __attribute__((ext_vector_type(8))) short s16x8;
typedef __attribute__((ext_vector_type(4))) unsigned int u32x4;
typedef __attribute__((ext_vector_type(2))) unsigned int u32x2;

__device__ __forceinline__ float bf2f(unsigned int b){ return __builtin_bit_cast(float, b << 16); }
__device__ __forceinline__ unsigned int f2bf(float f){          // RNE f32->bf16, low 16 bits
  unsigned int u = __builtin_bit_cast(unsigned int, f);
  return (u + 0x7FFFu + ((u >> 16) & 1u)) >> 16;
}
// packed RNE f32x2 -> bf16x2 (low word = first arg)
__device__ __forceinline__ unsigned int cvtpk(float lo, float hi){
  unsigned int r;
  asm("v_cvt_pk_bf16_f32 %0, %1, %2" : "=v"(r) : "v"(lo), "v"(hi));
  return r;
}
// monotone float->uint map: f1<f2 <=> map(f1)<map(f2); any finite value maps to nonzero
__device__ __forceinline__ unsigned int fmap(float f){
  unsigned int u = __builtin_bit_cast(unsigned int, f);
  return (u & 0x80000000u) ? ~u : (u | 0x80000000u);
}

// ---- detect edge_index element width: int64 (odd u32 slots all zero) vs int32 ----
extern "C" __global__ void k_detect(const unsigned int* __restrict__ e, int* __restrict__ flag){
  unsigned int v = e[2 * threadIdx.x + 1];
  unsigned long long b = __ballot(v != 0u);
  if (threadIdx.x == 0) *flag = (b == 0ull) ? 1 : 0;   // 1 => int64
}

// ---- counting sort by dst: histogram ----
extern "C" __global__ void k_hist(const void* __restrict__ eidx, const int* __restrict__ flag,
                                  unsigned int* __restrict__ cnt){
  int i = blockIdx.x * 256 + threadIdx.x;
  int d = (*flag) ? (int)((const long long*)eidx)[N_EDGES + i]
                  : ((const int*)eidx)[N_EDGES + i];
  atomicAdd(&cnt[d], 1u);
}

// ---- single-block exclusive scan over 50000 counters ----
extern "C" __global__ void __launch_bounds__(1024) k_scan(const unsigned int* __restrict__ cnt,
                                                          unsigned int* __restrict__ off){
  __shared__ unsigned int ps[1024];
  const int t = threadIdx.x;
  const int lo = t * 49;
  const int hi = (lo + 49 < N_NODES) ? lo + 49 : N_NODES;   // 49*1024 = 50176 >= 50000
  unsigned int s = 0;
  for (int i = lo; i < hi; i++) s += cnt[i];
  ps[t] = s; __syncthreads();
  for (int d = 1; d < 1024; d <<= 1){
    unsigned int v = (t >= d) ? ps[t - d] : 0u;
    __syncthreads();
    ps[t] += v;
    __syncthreads();
  }
  unsigned int run = (t > 0) ? ps[t - 1] : 0u;
  for (int i = lo; i < hi; i++){ off[i] = run; run += cnt[i]; }
}

// ---- scatter edges into dst-sorted order, packed (src | dst<<16) ----
extern "C" __global__ void k_bucket(const void* __restrict__ eidx, const int* __restrict__ flag,
                                    unsigned int* __restrict__ cur, unsigned int* __restrict__ sPair){
  int i = blockIdx.x * 256 + threadIdx.x;
  int s, d;
  if (*flag){
    const long long* p = (const long long*)eidx;
    s = (int)p[i]; d = (int)p[N_EDGES + i];
  } else {
    const int* p = (const int*)eidx;
    s = p[i]; d = p[N_EDGES + i];
  }
  unsigned int pos = atomicAdd(&cur[d], 1u);
  sPair[pos] = (unsigned int)s | ((unsigned int)d << 16);    // both < 50000 < 2^16
}

// ---- pre-swizzle W2^T / W3^T into MFMA A-frag order, bf16 ----
// lane l of block (mfG*8+ks) holds A[m=16*mfG+(l&15)][k=32*ks+8*(l>>4)+j], j=0..7
extern "C" __global__ void k_wswz(const float* __restrict__ W2, const float* __restrict__ W3,
                                  unsigned short* __restrict__ w2s, unsigned short* __restrict__ w3s){
  int t = blockIdx.x * 256 + threadIdx.x;              // 0..16383
  const float* W = (t & 8192) ? W3 : W2;
  unsigned short* o = (t & 8192) ? w3s : w2s;
  int r = t & 8191;
  int lane = r & 63, blk = r >> 6;
  int mfG = blk >> 3, ks = blk & 7;
  int m  = mfG * 16 + (lane & 15);
  int k0 = ks * 32 + (lane >> 4) * 8;
  u32x4 ov;
  #pragma unroll
  for (int j = 0; j < 4; j++){
    unsigned int lo = f2bf(W[(size_t)(k0 + 2*j    ) * 256 + m]);   // A[m][k] = W[k][m]
    unsigned int hi = f2bf(W[(size_t)(k0 + 2*j + 1) * 256 + m]);
    ov[j] = lo | (hi << 16);
  }
  *(u32x4*)(o + (size_t)r * 8) = ov;
}

// ---- per-node precompute: a = x@(W1a-W1b)+b1, c = x@W1b  (fp32 math, bf16 out) ----
extern "C" __global__ void __launch_bounds__(512) k_ac(
    const float* __restrict__ x, const float* __restrict__ W1, const float* __restrict__ b1,
    unsigned short* __restrict__ a, unsigned short* __restrict__ cc){
  const int t = threadIdx.x;
  const int n0 = blockIdx.x * 16;                      // 3125 blocks exactly
  const int col = t & 255, half = t >> 8;              // half 0 -> a, 1 -> c (wave-uniform)
  float acc[16];
  #pragma unroll
  for (int r = 0; r < 16; r++) acc[r] = 0.f;
  const float* wb = W1 + 128 * 256 + col;              // W1b column
  const float* xb = x + (size_t)n0 * 128;
  #pragma unroll 4
  for (int k = 0; k < 128; k++){
    float wv = wb[(size_t)k * 256];
    if (half == 0) wv = W1[(size_t)k * 256 + col] - wv;
    #pragma unroll
    for (int r = 0; r < 16; r++) acc[r] += xb[r * 128 + k] * wv;   // uniform -> s_load
  }
  float bias = (half == 0) ? b1[col] : 0.f;
  unsigned short* o = (half == 0) ? a : cc;
  #pragma unroll
  for (int r = 0; r < 16; r++)
    o[(size_t)(n0 + r) * 256 + col] = (unsigned short)f2bf(acc[r] + bias);
}

// ---- fused edge MLP on dst-sorted edges: 64 edges/block, 4 waves ----
// h1/h2 in fragment-linear LDS layout: 16B slot index = nf*512 + ks*64 + sub*16 + lane16
//   (channel c of edge e lives at slot [(e>>4)*512 + (c>>5)*64 + ((c>>3)&3)*16 + (e&15)],
//    byte (c&7)*2). B-frag read = sm + nf*8192 + ks*1024 + lane*16 -> conflict-free b128.
// h3 staged f32 row-major+XOR in two 32-row halves; float running max; fire-and-forget atomics.
extern "C" __global__ void __launch_bounds__(256, 4) k_edge(
    const unsigned short* __restrict__ a, const unsigned short* __restrict__ c,
    const s16x8* __restrict__ w2f, const s16x8* __restrict__ w3f,
    const float* __restrict__ b2, const float* __restrict__ b3,
    const unsigned int* __restrict__ sPair,
    unsigned int* __restrict__ outu){
  __shared__ unsigned char sm[32768];
  __shared__ int dstI[64];
  __shared__ int srcI[64];
  const int tid = threadIdx.x;
  const int lane = tid & 63;
  const int w = tid >> 6;

  // bijective XCD chunk swizzle: 12500 = 8*1562+4 -> consecutive blocks on same XCD
  const int bid = blockIdx.x;
  const int xcd = bid & 7, idx = bid >> 3;
  const int sb = (xcd < 4) ? xcd * 1563 : 4 * 1563 + (xcd - 4) * 1562;
  const int e0 = (sb + idx) * 64;

  // prefetch W2 ks=0 A-frags (no LDS dependency; overlaps index load + gather)
  s16x8 afp[4];
  #pragma unroll
  for (int mf = 0; mf < 4; mf++) afp[mf] = w2f[((w * 4 + mf) * 8 + 0) * 64 + lane];

  if (tid < 64){
    unsigned int pr = sPair[e0 + tid];
    srcI[tid] = (int)(pr & 0xFFFFu);
    dstI[tid] = (int)(pr >> 16);
  }
  __syncthreads();

  { // gather: h1 = relu(a[dst]+c[src]) -> fragment-linear LDS. 4 threads/edge, 64 ch each.
    const int e = tid >> 2, q = tid & 3;
    const unsigned short* pa = a + (size_t)dstI[e] * 256 + q * 64;   // sorted: cache-hot
    const unsigned short* pc = c + (size_t)srcI[e] * 256 + q * 64;
    unsigned char* base = sm + (e >> 4) * 8192 + (e & 15) * 16;
    #pragma unroll
    for (int j = 0; j < 8; j++){                        // chunk j: channels q*64+j*8 ..+7
      u32x4 ua = *(const u32x4*)(pa + j * 8);
      u32x4 uc = *(const u32x4*)(pc + j * 8);
      u32x4 ov;
      #pragma unroll
      for (int t2 = 0; t2 < 4; t2++){
        float lo = bf2f(ua[t2] & 0xFFFFu) + bf2f(uc[t2] & 0xFFFFu);
        float hi = __builtin_bit_cast(float, ua[t2] & 0xFFFF0000u) +
                   __builtin_bit_cast(float, uc[t2] & 0xFFFF0000u);
        ov[t2] = cvtpk(fmaxf(lo, 0.f), fmaxf(hi, 0.f));
      }
      *(u32x4*)(base + (q * 2 + (j >> 2)) * 1024 + (j & 3) * 256) = ov;
    }
  }
  __syncthreads();

  const int lm = lane & 15, g = lane >> 4;
  f32x4 acc[4][4];
  #pragma unroll
  for (int mf = 0; mf < 4; mf++)
    #pragma unroll
    for (int nf = 0; nf < 4; nf++) acc[mf][nf] = (f32x4){0.f, 0.f, 0.f, 0.f};

  // G1: h2^T = W2^T @ h1^T
  #pragma unroll
  for (int ks = 0; ks < 8; ks++){
    s16x8 af[4], bfr[4];
    #pragma unroll
    for (int mf = 0; mf < 4; mf++)
      af[mf] = (ks == 0) ? afp[mf] : w2f[((w * 4 + mf) * 8 + ks) * 64 + lane];
    #pragma unroll
    for (int nf = 0; nf < 4; nf++)
      bfr[nf] = *(const s16x8*)(sm + nf * 8192 + ks * 1024 + lane * 16);
    __builtin_amdgcn_s_setprio(1);
    #pragma unroll
    for (int mf = 0; mf < 4; mf++)
      #pragma unroll
      for (int nf = 0; nf < 4; nf++)
        acc[mf][nf] = __builtin_amdgcn_mfma_f32_16x16x32_bf16(af[mf], bfr[nf], acc[mf][nf], 0, 0, 0);
    __builtin_amdgcn_s_setprio(0);
  }

  // prefetch W3 ks=0 before the barrier
  #pragma unroll
  for (int mf = 0; mf < 4; mf++) afp[mf] = w3f[((w * 4 + mf) * 8 + 0) * 64 + lane];
  __syncthreads();   // all waves done reading h1

  { // bias2 + relu -> h2 bf16, fragment-linear, in place. lane owns ch m0..m0+3, row nf*16+lm.
    #pragma unroll
    for (int mf = 0; mf < 4; mf++){
      const int m0 = w * 64 + mf * 16 + g * 4;
      const f32x4 bb = *(const f32x4*)(b2 + m0);
      const int boff = (m0 >> 5) * 1024 + ((m0 >> 3) & 3) * 256 + lm * 16 + (m0 & 7) * 2;
      #pragma unroll
      for (int nf = 0; nf < 4; nf++){
        float v0 = fmaxf(acc[mf][nf][0] + bb[0], 0.f);
        float v1 = fmaxf(acc[mf][nf][1] + bb[1], 0.f);
        float v2 = fmaxf(acc[mf][nf][2] + bb[2], 0.f);
        float v3 = fmaxf(acc[mf][nf][3] + bb[3], 0.f);
        u32x2 pv = { cvtpk(v0, v1), cvtpk(v2, v3) };
        *(u32x2*)(sm + nf * 8192 + boff) = pv;
      }
    }
  }
  __syncthreads();

  // G2: h3^T = W3^T @ h2^T  (reuse acc)
  #pragma unroll
  for (int mf = 0; mf < 4; mf++)
    #pragma unroll
    for (int nf = 0; nf < 4; nf++) acc[mf][nf] = (f32x4){0.f, 0.f, 0.f, 0.f};
  #pragma unroll
  for (int ks = 0; ks < 8; ks++){
    s16x8 af[4], bfr[4];
    #pragma unroll
    for (int mf = 0; mf < 4; mf++)
      af[mf] = (ks == 0) ? afp[mf] : w3f[((w * 4 + mf) * 8 + ks) * 64 + lane];
    #pragma unroll
    for (int nf = 0; nf < 4; nf++)
      bfr[nf] = *(const s16x8*)(sm + nf * 8192 + ks * 1024 + lane * 16);
    __builtin_amdgcn_s_setprio(1);
    #pragma unroll
    for (int mf = 0; mf < 4; mf++)
      #pragma unroll
      for (int nf = 0; nf < 4; nf++)
        acc[mf][nf] = __builtin_amdgcn_mfma_f32_16x16x32_bf16(af[mf], bfr[nf], acc[mf][nf], 0, 0, 0);
    __builtin_amdgcn_s_setprio(0);
  }
  __syncthreads();   // all h2 reads done before h3 staging overwrites the buffer

  // h3 staging (f32 row-major + XOR) + per-dst-group float running max, two 32-row halves.
  float vmaxf = -__builtin_inff();
  int curDst = dstI[0];
  const int t4 = tid * 4;
  #pragma unroll
  for (int half = 0; half < 2; half++){
    #pragma unroll
    for (int mf = 0; mf < 4; mf++){
      const int m0 = w * 64 + mf * 16 + g * 4;
      const f32x4 bb = *(const f32x4*)(b3 + m0);
      #pragma unroll
      for (int nfl = 0; nfl < 2; nfl++){
        const int r = nfl * 16 + lm;                    // row within half
        const int nf = half * 2 + nfl;
        f32x4 v = { acc[mf][nf][0] + bb[0], acc[mf][nf][1] + bb[1],
                    acc[mf][nf][2] + bb[2], acc[mf][nf][3] + bb[3] };
        *(f32x4*)(sm + r * 1024 + ((m0 * 4) ^ ((r & 7) << 4))) = v;
      }
    }
    __syncthreads();
    for (int it = 0; it < 32; it++){
      float v = *(const float*)(sm + it * 1024 + (t4 ^ ((it & 7) << 4)));
      const int d = dstI[half * 32 + it];               // uniform across block
      if (d != curDst){                                 // flush previous group (coalesced 1KB)
        atomicMax(outu + (size_t)curDst * 256 + tid, fmap(vmaxf));
        curDst = d; vmaxf = -__builtin_inff();
      }
      vmaxf = fmaxf(vmaxf, v);
    }
    __syncthreads();                                    // scatter reads done before next staging
  }
  atomicMax(outu + (size_t)curDst * 256 + tid, fmap(vmaxf));   // final flush
}

// ---- unmap uint->float; untouched (0) cells = empty segments -> 0.0 ----
extern "C" __global__ void k_fix(u32x4* __restrict__ o){
  size_t i = (size_t)blockIdx.x * 256 + threadIdx.x;
  u32x4 u = o[i];
  #pragma unroll
  for (int j = 0; j < 4; j++)
    u[j] = (u[j] == 0u) ? 0u : ((u[j] & 0x80000000u) ? (u[j] ^ 0x80000000u) : ~u[j]);
  o[i] = u;
}

extern "C" void kernel_launch(void* const* d_in, const int* in_sizes, int n_in,
                              void* d_out, int out_size, void* d_ws, size_t ws_size,
                              hipStream_t stream){
  const float* x  = (const float*)d_in[0];
  const void*  ei = d_in[1];
  const float* W1 = (const float*)d_in[2];
  const float* b1 = (const float*)d_in[3];
  const float* W2 = (const float*)d_in[4];
  const float* b2 = (const float*)d_in[5];
  const float* W3 = (const float*)d_in[6];
  const float* b3 = (const float*)d_in[7];

  const size_t A_BYTES = (size_t)N_NODES * 256 * 2;   // 25.6 MB each for a, c
  const size_t W_BYTES = 256 * 256 * 2;               // 128 KB each swizzled weight
  const size_t P_BYTES = (size_t)N_EDGES * 4;         // 3.2 MB sorted pairs
  const size_t C_BYTES = 200704;                      // 50000 u32, padded
  char* ws = (char*)d_ws;
  size_t o = 0;
  unsigned short* a    = (unsigned short*)(ws + o); o += A_BYTES;
  unsigned short* cc   = (unsigned short*)(ws + o); o += A_BYTES;
  unsigned short* w2s  = (unsigned short*)(ws + o); o += W_BYTES;
  unsigned short* w3s  = (unsigned short*)(ws + o); o += W_BYTES;
  unsigned int*  sPair = (unsigned int*)(ws + o);   o += P_BYTES;
  unsigned int*  cnt   = (unsigned int*)(ws + o);   o += C_BYTES;
  unsigned int*  offA  = (unsigned int*)(ws + o);   o += C_BYTES;
  int* flag            = (int*)(ws + o);            o += 256;
  if (ws_size < o) return;   // insufficient scratch

  k_detect<<<1, 64, 0, stream>>>((const unsigned int*)ei, flag);
  hipMemsetAsync(cnt, 0, C_BYTES, stream);
  k_hist<<<N_EDGES / 256, 256, 0, stream>>>(ei, flag, cnt);
  k_scan<<<1, 1024, 0, stream>>>(cnt, offA);
  k_bucket<<<N_EDGES / 256, 256, 0, stream>>>(ei, flag, offA, sPair);
  k_wswz<<<64, 256, 0, stream>>>(W2, W3, w2s, w3s);
  k_ac<<<N_NODES / 16, 512, 0, stream>>>(x, W1, b1, a, cc);
  hipMemsetAsync(d_out, 0, (size_t)out_size * 4, stream);
  k_edge<<<N_EDGES / 64, 256, 0, stream>>>(a, cc, (const s16x8*)w2s, (const s16x8*)w3s,
                                           b2, b3, sPair, (unsigned int*)d_out);
  k_fix<<<out_size / 1024, 256, 0, stream>>>((u32x4*)d_out);
}

// Round 6
// 524.182 us; speedup vs baseline: 4.8598x; 1.3082x over previous
//
#include <hip/hip_runtime.h>
#include <stdint.h>

// EdgeConv fused: out[i] = max over edges (j->i) of MLP3(concat[x_i, x_j-x_i])
// Layer-1 split: e@W1 = x_i@(W1a-W1b) + x_j@W1b. Per-node ac[n] = [a|c] (fp16, MFMA-computed).
// Counting-sort edges by dst; k_edge: 64 edges/block, fp16 packed-ALU gather,
// fragment-linear LDS, f16 MFMA chain, per-dst-group running max, coalesced atomics.

#define N_NODES 50000
#define N_EDGES 800000

typedef __attribute__((ext_vector_type(4))) float f32x4;
typedef __attribute__((ext_vector_type(8))) _Float16 f16x8;
typedef __attribute__((ext_vector_type(4))) unsigned int u32x4;
typedef __attribute__((ext_vector_type(2))) unsigned int u32x2;

__device__ __forceinline__ unsigned int pkrtz(float a, float b){   // f32x2 -> packed fp16
  auto p = __builtin_amdgcn_cvt_pkrtz(a, b);                       // __fp16 ext_vector(2)
  return __builtin_bit_cast(unsigned int, p);
}
__device__ __forceinline__ unsigned int f16bits(float f){
  _Float16 h = (_Float16)f;
  return (unsigned int)__builtin_bit_cast(unsigned short, h);
}
// packed fp16: relu(a + b), 2 channels per instruction
__device__ __forceinline__ unsigned int pkadd_relu(unsigned int a, unsigned int b){
  unsigned int s, r;
  asm("v_pk_add_f16 %0, %1, %2" : "=v"(s) : "v"(a), "v"(b));
  asm("v_pk_max_f16 %0, %1, %2" : "=v"(r) : "v"(s), "v"(0u));
  return r;
}
// monotone float->uint map: f1<f2 <=> map(f1)<map(f2); any finite value maps to nonzero
__device__ __forceinline__ unsigned int fmap(float f){
  unsigned int u = __builtin_bit_cast(unsigned int, f);
  return (u & 0x80000000u) ? ~u : (u | 0x80000000u);
}
// int64 vs int32 edge_index: odd u32 slots of first 8 entries all zero <=> int64
__device__ __forceinline__ bool is64(const unsigned int* e){
  return (e[1] | e[3] | e[5] | e[7] | e[9] | e[11] | e[13] | e[15]) == 0u;
}

// ---- counting sort by dst: histogram (self-detecting index width) ----
extern "C" __global__ void k_hist(const void* __restrict__ eidx, unsigned int* __restrict__ cnt){
  int i = blockIdx.x * 256 + threadIdx.x;
  int d = is64((const unsigned int*)eidx)
        ? (int)((const long long*)eidx)[N_EDGES + i]
        : ((const int*)eidx)[N_EDGES + i];
  atomicAdd(&cnt[d], 1u);
}

// ---- single-block exclusive scan over 50000 counters ----
extern "C" __global__ void __launch_bounds__(1024) k_scan(const unsigned int* __restrict__ cnt,
                                                          unsigned int* __restrict__ off){
  __shared__ unsigned int ps[1024];
  const int t = threadIdx.x;
  const int lo = t * 49;
  const int hi = (lo + 49 < N_NODES) ? lo + 49 : N_NODES;   // 49*1024 >= 50000
  unsigned int s = 0;
  for (int i = lo; i < hi; i++) s += cnt[i];
  ps[t] = s; __syncthreads();
  for (int d = 1; d < 1024; d <<= 1){
    unsigned int v = (t >= d) ? ps[t - d] : 0u;
    __syncthreads();
    ps[t] += v;
    __syncthreads();
  }
  unsigned int run = (t > 0) ? ps[t - 1] : 0u;
  for (int i = lo; i < hi; i++){ off[i] = run; run += cnt[i]; }
}

// ---- scatter edges into dst-sorted order, packed (src | dst<<16) ----
extern "C" __global__ void k_bucket(const void* __restrict__ eidx,
                                    unsigned int* __restrict__ cur, unsigned int* __restrict__ sPair){
  int i = blockIdx.x * 256 + threadIdx.x;
  int s, d;
  if (is64((const unsigned int*)eidx)){
    const long long* p = (const long long*)eidx;
    s = (int)p[i]; d = (int)p[N_EDGES + i];
  } else {
    const int* p = (const int*)eidx;
    s = p[i]; d = p[N_EDGES + i];
  }
  unsigned int pos = atomicAdd(&cur[d], 1u);
  sPair[pos] = (unsigned int)s | ((unsigned int)d << 16);    // both < 50000 < 2^16
}

// ---- weight prep: W2^T, W3^T (256x256) and Wd (512x128) into fp16 MFMA A-frag order ----
// A-frag: lane l of block (mfG*KS+ks) holds A[m=16*mfG+(l&15)][k=32*ks+8*(l>>4)+j], j=0..7
extern "C" __global__ void k_wprep(const float* __restrict__ W1, const float* __restrict__ W2,
                                   const float* __restrict__ W3,
                                   unsigned short* __restrict__ w2s, unsigned short* __restrict__ w3s,
                                   unsigned short* __restrict__ wdf){
  int t = blockIdx.x * 256 + threadIdx.x;              // 0..24575
  if (t < 16384){                                      // W2 / W3: K=256, 8 ks-blocks
    const float* W = (t & 8192) ? W3 : W2;
    unsigned short* o = (t & 8192) ? w3s : w2s;
    int r = t & 8191, lane = r & 63, blk = r >> 6;
    int m  = (blk >> 3) * 16 + (lane & 15);
    int k0 = (blk & 7) * 32 + (lane >> 4) * 8;
    u32x4 ov;
    #pragma unroll
    for (int j = 0; j < 4; j++){
      unsigned int lo = f16bits(W[(size_t)(k0 + 2*j    ) * 256 + m]);   // A[m][k] = W[k][m]
      unsigned int hi = f16bits(W[(size_t)(k0 + 2*j + 1) * 256 + m]);
      ov[j] = lo | (hi << 16);
    }
    *(u32x4*)(o + (size_t)r * 8) = ov;
  } else {                                             // Wd: 512 rows, K=128, 4 ks-blocks
    int r = t - 16384, lane = r & 63, blk = r >> 6;    // blk 0..127
    int m  = (blk >> 2) * 16 + (lane & 15);            // 0..511
    int k0 = (blk & 3) * 32 + (lane >> 4) * 8;         // 0..127
    u32x4 ov;
    #pragma unroll
    for (int j = 0; j < 4; j++){
      float vlo, vhi;
      int ka = k0 + 2*j, kb = k0 + 2*j + 1;
      if (m < 256){
        vlo = W1[(size_t)ka * 256 + m] - W1[(size_t)(ka + 128) * 256 + m];
        vhi = W1[(size_t)kb * 256 + m] - W1[(size_t)(kb + 128) * 256 + m];
      } else {
        vlo = W1[(size_t)(ka + 128) * 256 + (m - 256)];
        vhi = W1[(size_t)(kb + 128) * 256 + (m - 256)];
      }
      ov[j] = f16bits(vlo) | (f16bits(vhi) << 16);
    }
    *(u32x4*)(wdf + (size_t)r * 8) = ov;
  }
}

// ---- per-node precompute via MFMA: ac[n] = [a|c] fp16, a=x@(W1a-W1b)+b1, c=x@W1b ----
// 64 nodes/block, 4 waves; x^T staged fp16 in fragment-linear LDS; out^T = Wd @ x^T.
extern "C" __global__ void __launch_bounds__(256) k_acm(
    const float* __restrict__ x, const unsigned short* __restrict__ wdf,
    const float* __restrict__ b1, unsigned short* __restrict__ acb){
  __shared__ unsigned char smx[16384];                 // 64 nodes x 128 ch fp16
  const int tid = threadIdx.x, lane = tid & 63, w = tid >> 6;
  const int n0 = blockIdx.x * 64;
  { // stage x (f32) -> fp16 B-frag layout: ch k of node n at slot (k>>5)*64+((k>>3)&3)*16+(n&15), +(n>>4)*256
    const int nl = tid >> 2, q = tid & 3;
    int node = n0 + nl; if (node > N_NODES - 1) node = N_NODES - 1;
    const f32x4* xp = (const f32x4*)(x + (size_t)node * 128 + q * 32);
    unsigned char* base = smx + (((nl >> 4) * 256 + q * 64 + (nl & 15)) << 4);
    #pragma unroll
    for (int s = 0; s < 4; s++){
      f32x4 v0 = xp[s * 2], v1 = xp[s * 2 + 1];
      u32x4 ov = { pkrtz(v0[0], v0[1]), pkrtz(v0[2], v0[3]),
                   pkrtz(v1[0], v1[1]), pkrtz(v1[2], v1[3]) };
      *(u32x4*)(base + s * 256) = ov;
    }
  }
  __syncthreads();
  const int lm = lane & 15, g = lane >> 4;
  f32x4 acc[8][4];
  #pragma unroll
  for (int mf = 0; mf < 8; mf++)
    #pragma unroll
    for (int nf = 0; nf < 4; nf++) acc[mf][nf] = (f32x4){0.f, 0.f, 0.f, 0.f};
  #pragma unroll
  for (int ks = 0; ks < 4; ks++){
    f16x8 af[8], bfr[4];
    #pragma unroll
    for (int mf = 0; mf < 8; mf++)
      af[mf] = __builtin_bit_cast(f16x8, *(const u32x4*)(wdf + (size_t)(((w * 8 + mf) * 4 + ks) * 64 + lane) * 8));
    #pragma unroll
    for (int nf = 0; nf < 4; nf++)
      bfr[nf] = __builtin_bit_cast(f16x8, *(const u32x4*)(smx + nf * 4096 + ks * 1024 + lane * 16));
    #pragma unroll
    for (int mf = 0; mf < 8; mf++)
      #pragma unroll
      for (int nf = 0; nf < 4; nf++)
        acc[mf][nf] = __builtin_amdgcn_mfma_f32_16x16x32_f16(af[mf], bfr[nf], acc[mf][nf], 0, 0, 0);
  }
  #pragma unroll
  for (int mf = 0; mf < 8; mf++){
    const int m0 = w * 128 + mf * 16 + g * 4;          // w<2 -> a half (bias), w>=2 -> c half
    f32x4 bb = (f32x4){0.f, 0.f, 0.f, 0.f};
    if (w < 2) bb = *(const f32x4*)(b1 + m0);
    #pragma unroll
    for (int nf = 0; nf < 4; nf++){
      int node = n0 + nf * 16 + lm;
      if (node < N_NODES){
        u32x2 pv = { pkrtz(acc[mf][nf][0] + bb[0], acc[mf][nf][1] + bb[1]),
                     pkrtz(acc[mf][nf][2] + bb[2], acc[mf][nf][3] + bb[3]) };
        *(u32x2*)(acb + (size_t)node * 512 + m0) = pv;
      }
    }
  }
}

// ---- fused edge MLP on dst-sorted edges: 64 edges/block, 4 waves, fp16 ----
// h1/h2 fragment-linear LDS: ch c of edge e at slot (e>>4)*512 + (c>>5)*64 + ((c>>3)&3)*16 + (e&15).
// B-frag read = sm + nf*8192 + ks*1024 + lane*16 -> conflict-free ds_read_b128.
extern "C" __global__ void __launch_bounds__(256, 4) k_edge(
    const unsigned short* __restrict__ acb,
    const unsigned short* __restrict__ w2f, const unsigned short* __restrict__ w3f,
    const float* __restrict__ b2, const float* __restrict__ b3,
    const unsigned int* __restrict__ sPair,
    unsigned int* __restrict__ outu){
  __shared__ unsigned char sm[32768];
  __shared__ int dstI[64];
  __shared__ int srcI[64];
  const int tid = threadIdx.x;
  const int lane = tid & 63;
  const int w = tid >> 6;

  // bijective XCD chunk swizzle: 12500 = 8*1562+4
  const int bid = blockIdx.x;
  const int xcd = bid & 7, idx = bid >> 3;
  const int sb = (xcd < 4) ? xcd * 1563 : 4 * 1563 + (xcd - 4) * 1562;
  const int e0 = (sb + idx) * 64;

  // prefetch W2 ks=0 A-frags
  f16x8 afp[4];
  #pragma unroll
  for (int mf = 0; mf < 4; mf++)
    afp[mf] = __builtin_bit_cast(f16x8, *(const u32x4*)(w2f + (size_t)(((w * 4 + mf) * 8 + 0) * 64 + lane) * 8));

  if (tid < 64){
    unsigned int pr = sPair[e0 + tid];
    srcI[tid] = (int)(pr & 0xFFFFu);
    dstI[tid] = (int)(pr >> 16);
  }
  __syncthreads();

  { // gather: h1 = relu(a[dst]+c[src]) via packed fp16 ALU. 4 threads/edge, 64 ch each.
    const int e = tid >> 2, q = tid & 3;
    const unsigned short* pa = acb + (size_t)dstI[e] * 512 + q * 64;         // a half (cache-hot)
    const unsigned short* pc = acb + (size_t)srcI[e] * 512 + 256 + q * 64;   // c half
    unsigned char* base = sm + (e >> 4) * 8192 + (e & 15) * 16;
    #pragma unroll
    for (int j = 0; j < 8; j++){                        // chunk j: channels q*64+j*8 ..+7
      u32x4 ua = *(const u32x4*)(pa + j * 8);
      u32x4 uc = *(const u32x4*)(pc + j * 8);
      u32x4 ov;
      #pragma unroll
      for (int t2 = 0; t2 < 4; t2++) ov[t2] = pkadd_relu(ua[t2], uc[t2]);
      *(u32x4*)(base + (q * 2 + (j >> 2)) * 1024 + (j & 3) * 256) = ov;
    }
  }
  __syncthreads();

  const int lm = lane & 15, g = lane >> 4;
  f32x4 acc[4][4];
  #pragma unroll
  for (int mf = 0; mf < 4; mf++)
    #pragma unroll
    for (int nf = 0; nf < 4; nf++) acc[mf][nf] = (f32x4){0.f, 0.f, 0.f, 0.f};

  // G1: h2^T = W2^T @ h1^T
  #pragma unroll
  for (int ks = 0; ks < 8; ks++){
    f16x8 af[4], bfr[4];
    #pragma unroll
    for (int mf = 0; mf < 4; mf++)
      af[mf] = (ks == 0) ? afp[mf]
             : __builtin_bit_cast(f16x8, *(const u32x4*)(w2f + (size_t)(((w * 4 + mf) * 8 + ks) * 64 + lane) * 8));
    #pragma unroll
    for (int nf = 0; nf < 4; nf++)
      bfr[nf] = __builtin_bit_cast(f16x8, *(const u32x4*)(sm + nf * 8192 + ks * 1024 + lane * 16));
    __builtin_amdgcn_s_setprio(1);
    #pragma unroll
    for (int mf = 0; mf < 4; mf++)
      #pragma unroll
      for (int nf = 0; nf < 4; nf++)
        acc[mf][nf] = __builtin_amdgcn_mfma_f32_16x16x32_f16(af[mf], bfr[nf], acc[mf][nf], 0, 0, 0);
    __builtin_amdgcn_s_setprio(0);
  }

  // prefetch W3 ks=0 before the barrier
  #pragma unroll
  for (int mf = 0; mf < 4; mf++)
    afp[mf] = __builtin_bit_cast(f16x8, *(const u32x4*)(w3f + (size_t)(((w * 4 + mf) * 8 + 0) * 64 + lane) * 8));
  __syncthreads();   // all waves done reading h1

  { // bias2 + relu -> h2 fp16, fragment-linear, in place
    #pragma unroll
    for (int mf = 0; mf < 4; mf++){
      const int m0 = w * 64 + mf * 16 + g * 4;
      const f32x4 bb = *(const f32x4*)(b2 + m0);
      const int boff = (m0 >> 5) * 1024 + ((m0 >> 3) & 3) * 256 + lm * 16 + (m0 & 7) * 2;
      #pragma unroll
      for (int nf = 0; nf < 4; nf++){
        float v0 = fmaxf(acc[mf][nf][0] + bb[0], 0.f);
        float v1 = fmaxf(acc[mf][nf][1] + bb[1], 0.f);
        float v2 = fmaxf(acc[mf][nf][2] + bb[2], 0.f);
        float v3 = fmaxf(acc[mf][nf][3] + bb[3], 0.f);
        u32x2 pv = { pkrtz(v0, v1), pkrtz(v2, v3) };
        *(u32x2*)(sm + nf * 8192 + boff) = pv;
      }
    }
  }
  __syncthreads();

  // G2: h3^T = W3^T @ h2^T  (reuse acc)
  #pragma unroll
  for (int mf = 0; mf < 4; mf++)
    #pragma unroll
    for (int nf = 0; nf < 4; nf++) acc[mf][nf] = (f32x4){0.f, 0.f, 0.f, 0.f};
  #pragma unroll
  for (int ks = 0; ks < 8; ks++){
    f16x8 af[4], bfr[4];
    #pragma unroll
    for (int mf = 0; mf < 4; mf++)
      af[mf] = (ks == 0) ? afp[mf]
             : __builtin_bit_cast(f16x8, *(const u32x4*)(w3f + (size_t)(((w * 4 + mf) * 8 + ks) * 64 + lane) * 8));
    #pragma unroll
    for (int nf = 0; nf < 4; nf++)
      bfr[nf] = __builtin_bit_cast(f16x8, *(const u32x4*)(sm + nf * 8192 + ks * 1024 + lane * 16));
    __builtin_amdgcn_s_setprio(1);
    #pragma unroll
    for (int mf = 0; mf < 4; mf++)
      #pragma unroll
      for (int nf = 0; nf < 4; nf++)
        acc[mf][nf] = __builtin_amdgcn_mfma_f32_16x16x32_f16(af[mf], bfr[nf], acc[mf][nf], 0, 0, 0);
    __builtin_amdgcn_s_setprio(0);
  }
  __syncthreads();   // all h2 reads done before h3 staging overwrites the buffer

  // h3 staging (f32 row-major + XOR) + per-dst-group float running max, two 32-row halves.
  float vmaxf = -__builtin_inff();
  int curDst = dstI[0];
  const int t4 = tid * 4;
  #pragma unroll
  for (int half = 0; half < 2; half++){
    #pragma unroll
    for (int mf = 0; mf < 4; mf++){
      const int m0 = w * 64 + mf * 16 + g * 4;
      const f32x4 bb = *(const f32x4*)(b3 + m0);
      #pragma unroll
      for (int nfl = 0; nfl < 2; nfl++){
        const int r = nfl * 16 + lm;                    // row within half
        const int nf = half * 2 + nfl;
        f32x4 v = { acc[mf][nf][0] + bb[0], acc[mf][nf][1] + bb[1],
                    acc[mf][nf][2] + bb[2], acc[mf][nf][3] + bb[3] };
        *(f32x4*)(sm + r * 1024 + ((m0 * 4) ^ ((r & 7) << 4))) = v;
      }
    }
    __syncthreads();
    for (int it = 0; it < 32; it++){
      float v = *(const float*)(sm + it * 1024 + (t4 ^ ((it & 7) << 4)));
      const int d = dstI[half * 32 + it];               // uniform across block
      if (d != curDst){                                 // flush previous group (coalesced 1KB)
        atomicMax(outu + (size_t)curDst * 256 + tid, fmap(vmaxf));
        curDst = d; vmaxf = -__builtin_inff();
      }
      vmaxf = fmaxf(vmaxf, v);
    }
    __syncthreads();                                    // scatter reads done before next staging
  }
  atomicMax(outu + (size_t)curDst * 256 + tid, fmap(vmaxf));   // final flush
}

// ---- unmap uint->float; untouched (0) cells = empty segments -> 0.0 ----
extern "C" __global__ void k_fix(u32x4* __restrict__ o){
  size_t i = (size_t)blockIdx.x * 256 + threadIdx.x;
  u32x4 u = o[i];
  #pragma unroll
  for (int j = 0; j < 4; j++)
    u[j] = (u[j] == 0u) ? 0u : ((u[j] & 0x80000000u) ? (u[j] ^ 0x80000000u) : ~u[j]);
  o[i] = u;
}

extern "C" void kernel_launch(void* const* d_in, const int* in_sizes, int n_in,
                              void* d_out, int out_size, void* d_ws, size_t ws_size,
                              hipStream_t stream){
  const float* x  = (const float*)d_in[0];
  const void*  ei = d_in[1];
  const float* W1 = (const float*)d_in[2];
  const float* b1 = (const float*)d_in[3];
  const float* W2 = (const float*)d_in[4];
  const float* b2 = (const float*)d_in[5];
  const float* W3 = (const float*)d_in[6];
  const float* b3 = (const float*)d_in[7];

  const size_t AC_BYTES = (size_t)N_NODES * 512 * 2;  // 51.2 MB combined [a|c] fp16
  const size_t W_BYTES  = 256 * 256 * 2;              // 128 KB each: w2s, w3s, wdf
  const size_t P_BYTES  = (size_t)N_EDGES * 4;        // 3.2 MB sorted pairs
  const size_t C_BYTES  = 200704;                     // 50000 u32, padded
  char* ws = (char*)d_ws;
  size_t o = 0;
  unsigned short* acb  = (unsigned short*)(ws + o); o += AC_BYTES;
  unsigned short* w2s  = (unsigned short*)(ws + o); o += W_BYTES;
  unsigned short* w3s  = (unsigned short*)(ws + o); o += W_BYTES;
  unsigned short* wdf  = (unsigned short*)(ws + o); o += W_BYTES;   // 512*128*2 = 128 KB
  unsigned int*  sPair = (unsigned int*)(ws + o);   o += P_BYTES;
  unsigned int*  cnt   = (unsigned int*)(ws + o);   o += C_BYTES;
  unsigned int*  offA  = (unsigned int*)(ws + o);   o += C_BYTES;
  if (ws_size < o) return;   // insufficient scratch

  (void)hipMemsetAsync(cnt, 0, C_BYTES, stream);
  k_hist<<<N_EDGES / 256, 256, 0, stream>>>(ei, cnt);
  k_scan<<<1, 1024, 0, stream>>>(cnt, offA);
  k_bucket<<<N_EDGES / 256, 256, 0, stream>>>(ei, offA, sPair);
  k_wprep<<<96, 256, 0, stream>>>(W1, W2, W3, w2s, w3s, wdf);
  k_acm<<<(N_NODES + 63) / 64, 256, 0, stream>>>(x, wdf, b1, acb);
  (void)hipMemsetAsync(d_out, 0, (size_t)out_size * 4, stream);
  k_edge<<<N_EDGES / 64, 256, 0, stream>>>(acb, w2s, w3s, b2, b3, sPair, (unsigned int*)d_out);
  k_fix<<<out_size / 1024, 256, 0, stream>>>((u32x4*)d_out);
}